// Round 2
// baseline (381.938 us; speedup 1.0000x reference)
//
#include <hip/hip_runtime.h>

// Problem constants: B=32, T=1024, IN=1024, OUT=1024
// M = B*T = 32768, K = IN = 1024, N = OUT = 1024
#define M_DIM 32768
#define N_DIM 1024
#define K_DIM 1024
#define T_DIM 1024
#define B_DIM 32
#define NCHUNK 16
#define CHUNK_T 64    // T_DIM / NCHUNK; one chunk per GEMM wave-half (wm)

typedef unsigned int uint32;
typedef __attribute__((ext_vector_type(8))) short short8;       // 8 bf16 (MFMA A/B frag)
typedef __attribute__((ext_vector_type(8))) unsigned short ushort8v;
typedef __attribute__((ext_vector_type(4))) float floatx4;      // MFMA C/D frag

__device__ __forceinline__ unsigned short f2bf(float f) {
    uint32 u = __float_as_uint(f);
    uint32 r = u + 0x7fffu + ((u >> 16) & 1u);
    return (unsigned short)(r >> 16);
}

__device__ __forceinline__ void async_load16(const void* g, void* s) {
    __builtin_amdgcn_global_load_lds(
        (const __attribute__((address_space(1))) void*)g,
        (__attribute__((address_space(3))) void*)s,
        16, 0, 0);
}

__device__ __forceinline__ uint32 cvt_pk_bf16(float lo, float hi) {
    uint32 d;
    asm volatile("v_cvt_pk_bf16_f32 %0, %1, %2" : "=v"(d) : "v"(lo), "v"(hi));
    return d;
}

// ---------------------------------------------------------------------------
// fp32 -> bf16 cast, 8 elems/thread (16B store). Now only used for W (2 MB).
// ---------------------------------------------------------------------------
__global__ void cast_f32_bf16_x8(const float* __restrict__ src,
                                 unsigned short* __restrict__ dst, int n8) {
    int i = blockIdx.x * blockDim.x + threadIdx.x;
    if (i < n8) {
        const float4* s4 = (const float4*)src;
        float4 v0 = s4[(size_t)i * 2];
        float4 v1 = s4[(size_t)i * 2 + 1];
        ushort8v o;
        o[0] = f2bf(v0.x); o[1] = f2bf(v0.y); o[2] = f2bf(v0.z); o[3] = f2bf(v0.w);
        o[4] = f2bf(v1.x); o[5] = f2bf(v1.y); o[6] = f2bf(v1.z); o[7] = f2bf(v1.w);
        ((ushort8v*)dst)[i] = o;
    }
}

// ---------------------------------------------------------------------------
// bf16 MFMA GEMM with FUSED fp32->bf16 cast of A (reads X fp32 directly):
//   C[m,n] = sum_k A[m,k]*W[n,k] + bias[n]
// 128x128 tile, BK=64. A is reg-staged: global fp32 -> v_cvt_pk_bf16_f32 ->
// ds_write_b128 (XOR-swizzled layout identical to the gload_lds path).
// A-loads for tile kt+1 are issued during tile kt's MFMA phase (T14).
// B (2 MB, L2-resident) keeps global_load_lds with pre-swizzled source.
// Epilogue: bias add + bf16 C write + fused chunk-carry (unchanged).
// ---------------------------------------------------------------------------
__global__ __launch_bounds__(256) void gemm_mfma_f32A(
    const float* __restrict__ A,            // [M, K] fp32 (= X)
    const unsigned short* __restrict__ Bw,  // [N, K] bf16
    const float* __restrict__ bias,         // [N]
    const float* __restrict__ decay,        // [N]
    unsigned short* outBf,                  // [M, N] bf16 (or null)
    float* outF,                            // [M, N] fp32 (or null)
    float* carry) {                         // [B, NCHUNK, N] (or null)
    __shared__ unsigned short As[128 * 64];
    __shared__ unsigned short Bs[128 * 64];

    const int tid  = threadIdx.x;
    const int lane = tid & 63;
    const int wid  = tid >> 6;
    const int l15  = lane & 15;
    const int quad = lane >> 4;
    const int wm   = wid >> 1;
    const int wn   = wid & 1;

    // XCD-aware remap (grid is (8, 256) -> L in [0, 2048))
    const int L    = blockIdx.y * gridDim.x + blockIdx.x;
    const int xcd  = L & 7;
    const int s    = L >> 3;
    const int bn0  = (s & 7) * 128;                 // N-tile
    const int bm0  = (xcd * 32 + (s >> 3)) * 128;   // M-panel

    // A-staging mapping: thread t owns, for p=0..3, (row = p*32 + t>>3,
    // 8-col chunk ch = t&7) -> 8 fp32 loads -> 4 cvt_pk -> 1 ds_write_b128.
    const int arow = tid >> 3;
    const int ach  = tid & 7;
    const float* aBase = A + (size_t)(bm0 + arow) * K_DIM + ach * 8;

    floatx4 acc[4][4];
#pragma unroll
    for (int i = 0; i < 4; ++i)
#pragma unroll
        for (int j = 0; j < 4; ++j)
            acc[i][j] = (floatx4){0.f, 0.f, 0.f, 0.f};

    // Prologue: load A-tile 0 into regs
    float4 ar[4][2];
#pragma unroll
    for (int p = 0; p < 4; ++p) {
        const float4* src = (const float4*)(aBase + (size_t)p * 32 * K_DIM);
        ar[p][0] = src[0];
        ar[p][1] = src[1];
    }

    const int NT = K_DIM / 64;
    for (int kt = 0; kt < NT; ++kt) {
        const int k0 = kt * 64;
        // B staging via global_load_lds (source pre-swizzled)
#pragma unroll
        for (int q = 0; q < 4; ++q) {
            int slot = q * 256 + tid;
            int row  = slot >> 3;
            int ch   = slot & 7;
            int sc   = ch ^ (row & 7);
            async_load16(Bw + (size_t)(bn0 + row) * K_DIM + k0 + sc * 8,
                         &Bs[(q * 256 + wid * 64) * 8]);
        }
        // A: cvt staged regs -> bf16, ds_write with XOR swizzle
#pragma unroll
        for (int p = 0; p < 4; ++p) {
            int row = p * 32 + arow;
            uint4 w;
            w.x = cvt_pk_bf16(ar[p][0].x, ar[p][0].y);
            w.y = cvt_pk_bf16(ar[p][0].z, ar[p][0].w);
            w.z = cvt_pk_bf16(ar[p][1].x, ar[p][1].y);
            w.w = cvt_pk_bf16(ar[p][1].z, ar[p][1].w);
            *(uint4*)&As[row * 64 + ((ach ^ (row & 7)) * 8)] = w;
        }
        __syncthreads();

        // Prefetch next A-tile into regs (overlaps with MFMA phase)
        if (kt + 1 < NT) {
            const float* nb = aBase + (size_t)(kt + 1) * 64;
#pragma unroll
            for (int p = 0; p < 4; ++p) {
                const float4* src = (const float4*)(nb + (size_t)p * 32 * K_DIM);
                ar[p][0] = src[0];
                ar[p][1] = src[1];
            }
        }

#pragma unroll
        for (int ks = 0; ks < 2; ++ks) {
            short8 af[4], bfr[4];
#pragma unroll
            for (int i = 0; i < 4; ++i) {
                int r = wm * 64 + i * 16 + l15;
                int c = ks * 4 + quad;
                af[i] = *(const short8*)&As[r * 64 + ((c ^ (r & 7)) * 8)];
            }
#pragma unroll
            for (int j = 0; j < 4; ++j) {
                int r = wn * 64 + j * 16 + l15;
                int c = ks * 4 + quad;
                bfr[j] = *(const short8*)&Bs[r * 64 + ((c ^ (r & 7)) * 8)];
            }
#pragma unroll
            for (int i = 0; i < 4; ++i)
#pragma unroll
                for (int j = 0; j < 4; ++j)
                    acc[i][j] = __builtin_amdgcn_mfma_f32_16x16x32_bf16(
                        af[i], bfr[j], acc[i][j], 0, 0, 0);
        }
        __syncthreads();
    }

    // C/D layout: col = lane&15, row = quad*4 + reg
#pragma unroll
    for (int j = 0; j < 4; ++j) {
        int col = bn0 + wn * 64 + j * 16 + l15;
        float bb = bias[col];
#pragma unroll
        for (int i = 0; i < 4; ++i) {
            int rowb = bm0 + wm * 64 + i * 16 + quad * 4;
#pragma unroll
            for (int r = 0; r < 4; ++r) {
                float v = acc[i][j][r] + bb;
                size_t idx = (size_t)(rowb + r) * N_DIM + col;
                if (outBf) outBf[idx] = f2bf(v);
                else       outF[idx]  = v;
            }
        }
    }

    // ---- fused chunk-carry epilogue ----
    // U = (1-a)*sum_{rloc} a^(63-rloc)*acc + bias*(1-a^64), rloc = i*16+quad*4+r
    if (carry) {
        const int bIdx = bm0 >> 10;                       // / T_DIM
        const int g    = ((bm0 & (T_DIM - 1)) >> 6) + wm; // chunk index
#pragma unroll
        for (int j = 0; j < 4; ++j) {
            int col = bn0 + wn * 64 + j * 16 + l15;
            float a   = decay[col];
            float bb  = bias[col];
            float a2  = a * a;
            float a4  = a2 * a2;
            float a8  = a4 * a4;
            float a12 = a8 * a4;
            float a64 = a12 * a4;          // a^16
            a64 = a64 * a64;               // a^32
            a64 = a64 * a64;               // a^64
            float w = (quad == 0) ? a12 : (quad == 1) ? a8
                    : (quad == 2) ? a4  : 1.0f;
            float sacc = 0.f;
#pragma unroll
            for (int i = 3; i >= 0; --i) {
#pragma unroll
                for (int r = 3; r >= 0; --r) {
                    sacc += w * acc[i][j][r];
                    w *= a;
                }
                if (i) w *= a12;           // row gap 13 across fragments
            }
            sacc += __shfl_xor(sacc, 16);
            sacc += __shfl_xor(sacc, 32);
            float U = (1.0f - a) * sacc + bb * (1.0f - a64);
            if (quad == 0)
                carry[((size_t)bIdx * NCHUNK + g) * N_DIM + col] = U;
        }
    }
}

// ---------------------------------------------------------------------------
// Apply pass: prefix-combine per-chunk carries, then local scan over
// CHUNK_T=64 steps, 2-wide over o. 262144 threads = 16 waves/CU.
// ---------------------------------------------------------------------------
__global__ __launch_bounds__(256) void scan_apply2(
    const uint32* __restrict__ cur32,         // [M, N/2] (bf16 pairs)
    const float* __restrict__ decay,
    const float* __restrict__ carry,          // [B, NCHUNK, N]
    float* __restrict__ out) {                // [M, N] fp32
    int tid   = blockIdx.x * 256 + threadIdx.x;   // 0 .. 262143
    int o2    = tid & 511;
    int chunk = (tid >> 9) & (NCHUNK - 1);
    int b     = tid >> 13;
    int o     = o2 * 2;
    size_t base = ((size_t)b * T_DIM + (size_t)chunk * CHUNK_T) * (N_DIM / 2) + o2;
    float2 a2 = *(const float2*)&decay[o];
    float a0 = a2.x, a1 = a2.y;
    float c0 = 1.f - a0, c1 = 1.f - a1;

    float A0 = a0, A1 = a1;
#pragma unroll
    for (int i = 0; i < 6; ++i) { A0 *= A0; A1 *= A1; }   // a^64

    float u0 = 0.f, u1 = 0.f;
    const float* cb = carry + (size_t)b * NCHUNK * N_DIM + o;
    for (int i = 0; i < chunk; ++i) {         // wave-uniform trip count
        float2 cv = *(const float2*)&cb[(size_t)i * N_DIM];
        u0 = cv.x + A0 * u0;
        u1 = cv.y + A1 * u1;
    }

    float2* out2 = (float2*)out;
    for (int t0 = 0; t0 < CHUNK_T; t0 += 32) {
        uint32 x[32];
#pragma unroll
        for (int k = 0; k < 32; ++k)
            x[k] = cur32[base + (size_t)(t0 + k) * (N_DIM / 2)];
#pragma unroll
        for (int k = 0; k < 32; ++k) {
            float lo = __uint_as_float(x[k] << 16);
            float hi = __uint_as_float(x[k] & 0xffff0000u);
            u0 = a0 * u0 + c0 * lo;
            u1 = a1 * u1 + c1 * hi;
            out2[base + (size_t)(t0 + k) * (N_DIM / 2)] = (float2){u0, u1};
        }
    }
}

// ---------------------------------------------------------------------------
// Fallbacks (only used if workspace too small for the bf16 path)
// ---------------------------------------------------------------------------
__global__ void scan_f32_inplace(float* __restrict__ buf,
                                 const float* __restrict__ decay) {
    int tid = blockIdx.x * 64 + threadIdx.x;
    int o = tid & (N_DIM - 1);
    size_t base = ((size_t)(tid >> 10) << 20) + o;
    float a = decay[o];
    float c = 1.f - a;
    float u = 0.f;
    for (int t0 = 0; t0 < 1024; t0 += 16) {
        float x[16];
#pragma unroll
        for (int k = 0; k < 16; ++k)
            x[k] = buf[base + (size_t)(t0 + k) * N_DIM];
#pragma unroll
        for (int k = 0; k < 16; ++k) {
            u = a * u + c * x[k];
            buf[base + (size_t)(t0 + k) * N_DIM] = u;
        }
    }
}

__global__ void gemm_naive(const float* __restrict__ X, const float* __restrict__ W,
                           const float* __restrict__ bias, float* __restrict__ out) {
    __shared__ float As[16][17], Bs[16][17];
    int tx = threadIdx.x, ty = threadIdx.y;
    int m0 = blockIdx.y * 16, n0 = blockIdx.x * 16;
    float acc = 0.f;
    for (int k0 = 0; k0 < K_DIM; k0 += 16) {
        As[ty][tx] = X[(size_t)(m0 + ty) * K_DIM + k0 + tx];
        Bs[ty][tx] = W[(size_t)(n0 + ty) * K_DIM + k0 + tx];
        __syncthreads();
#pragma unroll
        for (int kk = 0; kk < 16; ++kk) acc += As[ty][kk] * Bs[tx][kk];
        __syncthreads();
    }
    out[(size_t)(m0 + ty) * N_DIM + n0 + tx] = acc + bias[n0 + tx];
}

// ---------------------------------------------------------------------------
extern "C" void kernel_launch(void* const* d_in, const int* in_sizes, int n_in,
                              void* d_out, int out_size, void* d_ws, size_t ws_size,
                              hipStream_t stream) {
    const float* X     = (const float*)d_in[0];  // [B,T,IN]  = [M,K]
    const float* Wt    = (const float*)d_in[1];  // [OUT,IN]  = [N,K]
    const float* bias  = (const float*)d_in[2];  // [OUT]
    const float* decay = (const float*)d_in[3];  // [OUT]
    float* out = (float*)d_out;                  // [B,T,OUT] = [M,N]

    const size_t W_bytes  = (size_t)N_DIM * K_DIM * 2;            // 2 MB
    const size_t C_bytes  = (size_t)M_DIM * N_DIM * 2;            // 64 MB
    const size_t cr_bytes = (size_t)B_DIM * NCHUNK * N_DIM * 4;   // 2 MB
    const size_t need_mid  = W_bytes;
    const size_t need_full = W_bytes + C_bytes + cr_bytes;

    const int nW8 = N_DIM * K_DIM / 8;

    if (ws_size >= need_full) {
        unsigned short* Wbf = (unsigned short*)d_ws;
        unsigned short* Cbf = (unsigned short*)((char*)d_ws + W_bytes);
        float* carry = (float*)((char*)d_ws + W_bytes + C_bytes);
        cast_f32_bf16_x8<<<(nW8 + 255) / 256, 256, 0, stream>>>(Wt, Wbf, nW8);
        gemm_mfma_f32A<<<dim3(N_DIM / 128, M_DIM / 128), 256, 0, stream>>>(
            X, Wbf, bias, decay, Cbf, nullptr, carry);
        const int apply_threads = B_DIM * NCHUNK * N_DIM / 2;     // 262144
        scan_apply2<<<apply_threads / 256, 256, 0, stream>>>(
            (const uint32*)Cbf, decay, carry, out);
    } else if (ws_size >= need_mid) {
        unsigned short* Wbf = (unsigned short*)d_ws;
        cast_f32_bf16_x8<<<(nW8 + 255) / 256, 256, 0, stream>>>(Wt, Wbf, nW8);
        gemm_mfma_f32A<<<dim3(N_DIM / 128, M_DIM / 128), 256, 0, stream>>>(
            X, Wbf, bias, decay, nullptr, out, nullptr);
        scan_f32_inplace<<<512, 64, 0, stream>>>(out, decay);
    } else {
        gemm_naive<<<dim3(N_DIM / 16, M_DIM / 16), dim3(16, 16), 0, stream>>>(X, Wt, bias, out);
        scan_f32_inplace<<<512, 64, 0, stream>>>(out, decay);
    }
}

// Round 3
// 381.443 us; speedup vs baseline: 1.0013x; 1.0013x over previous
//
#include <hip/hip_runtime.h>

// Problem constants: B=32, T=1024, IN=1024, OUT=1024
// M = B*T = 32768, K = IN = 1024, N = OUT = 1024
#define M_DIM 32768
#define N_DIM 1024
#define K_DIM 1024
#define T_DIM 1024
#define B_DIM 32
#define NCHUNK 16
#define CHUNK_T 64    // T_DIM / NCHUNK; one chunk per GEMM wave-half (wm)

typedef unsigned int uint32;
typedef __attribute__((ext_vector_type(8))) short short8;       // 8 bf16 (MFMA A/B frag)
typedef __attribute__((ext_vector_type(8))) unsigned short ushort8v;
typedef __attribute__((ext_vector_type(4))) float floatx4;      // MFMA C/D frag

__device__ __forceinline__ unsigned short f2bf(float f) {
    uint32 u = __float_as_uint(f);
    uint32 r = u + 0x7fffu + ((u >> 16) & 1u);
    return (unsigned short)(r >> 16);
}

__device__ __forceinline__ void async_load16(const void* g, void* s) {
    __builtin_amdgcn_global_load_lds(
        (const __attribute__((address_space(1))) void*)g,
        (__attribute__((address_space(3))) void*)s,
        16, 0, 0);
}

__device__ __forceinline__ uint32 cvt_pk_bf16(float lo, float hi) {
    uint32 d;
    asm volatile("v_cvt_pk_bf16_f32 %0, %1, %2" : "=v"(d) : "v"(lo), "v"(hi));
    return d;
}

union PK4 { uint32 u[4]; short8 s; };

// ---------------------------------------------------------------------------
// fp32 -> bf16 cast, 8 elems/thread (16B store). Only used for W (4 MB read).
// ---------------------------------------------------------------------------
__global__ void cast_f32_bf16_x8(const float* __restrict__ src,
                                 unsigned short* __restrict__ dst, int n8) {
    int i = blockIdx.x * blockDim.x + threadIdx.x;
    if (i < n8) {
        const float4* s4 = (const float4*)src;
        float4 v0 = s4[(size_t)i * 2];
        float4 v1 = s4[(size_t)i * 2 + 1];
        ushort8v o;
        o[0] = f2bf(v0.x); o[1] = f2bf(v0.y); o[2] = f2bf(v0.z); o[3] = f2bf(v0.w);
        o[4] = f2bf(v1.x); o[5] = f2bf(v1.y); o[6] = f2bf(v1.z); o[7] = f2bf(v1.w);
        ((ushort8v*)dst)[i] = o;
    }
}

// ---------------------------------------------------------------------------
// bf16 MFMA GEMM reading A as fp32 DIRECTLY (no pre-cast kernel):
//   C[m,n] = sum_k A[m,k]*W[n,k] + bias[n]
// 128x128 tile, BK=64. A staged as fp32 into LDS via global_load_lds (async
// preserved — R2's regression came from losing this). fp32->bf16 happens at
// fragment-read time: 2x ds_read_b128 + 4x v_cvt_pk_bf16_f32 per A-frag.
// XOR swizzle on 16B chunks, pre-applied to the global SOURCE address
// (linear LDS dest as global_load_lds requires), inverse applied on read.
// B (2 MB bf16, L2-resident) unchanged. Epilogue: bias + bf16 C write +
// fused chunk-carry (unchanged from R1, harness-verified).
// ---------------------------------------------------------------------------
__global__ __launch_bounds__(256) void gemm_mfma_f32lds(
    const float* __restrict__ A,            // [M, K] fp32 (= X)
    const unsigned short* __restrict__ Bw,  // [N, K] bf16
    const float* __restrict__ bias,         // [N]
    const float* __restrict__ decay,        // [N]
    unsigned short* outBf,                  // [M, N] bf16 (or null)
    float* outF,                            // [M, N] fp32 (or null)
    float* carry) {                         // [B, NCHUNK, N] (or null)
    __shared__ float Asf[128 * 64];                 // 32 KB (fp32 A tile)
    __shared__ unsigned short Bs[128 * 64];         // 16 KB (bf16 B tile)

    const int tid  = threadIdx.x;
    const int lane = tid & 63;
    const int wid  = tid >> 6;
    const int l15  = lane & 15;
    const int quad = lane >> 4;
    const int wm   = wid >> 1;
    const int wn   = wid & 1;

    // XCD-aware remap (grid is (8, 256) -> L in [0, 2048))
    const int L    = blockIdx.y * gridDim.x + blockIdx.x;
    const int xcd  = L & 7;
    const int s    = L >> 3;
    const int bn0  = (s & 7) * 128;                 // N-tile
    const int bm0  = (xcd * 32 + (s >> 3)) * 128;   // M-panel

    floatx4 acc[4][4];
#pragma unroll
    for (int i = 0; i < 4; ++i)
#pragma unroll
        for (int j = 0; j < 4; ++j)
            acc[i][j] = (floatx4){0.f, 0.f, 0.f, 0.f};

    const int NT = K_DIM / 64;
    for (int kt = 0; kt < NT; ++kt) {
        const int k0 = kt * 64;
        // A staging: fp32 tile = 32 KB = 8 issues x 256 thr x 16B.
        // Row = 64 floats = 16 chunks of 16B; source chunk pre-swizzled
        // sc = ch ^ (row & 15); LDS dest linear.
#pragma unroll
        for (int q = 0; q < 8; ++q) {
            int slot = q * 256 + tid;
            int row  = slot >> 4;
            int ch   = slot & 15;
            int sc   = ch ^ (row & 15);
            async_load16(A + (size_t)(bm0 + row) * K_DIM + k0 + sc * 4,
                         &Asf[(q * 256 + wid * 64) * 4]);
        }
        // B staging: bf16 tile = 16 KB = 4 issues, 8 chunks/row, XOR (row&7).
#pragma unroll
        for (int q = 0; q < 4; ++q) {
            int slot = q * 256 + tid;
            int row  = slot >> 3;
            int ch   = slot & 7;
            int sc   = ch ^ (row & 7);
            async_load16(Bw + (size_t)(bn0 + row) * K_DIM + k0 + sc * 8,
                         &Bs[(q * 256 + wid * 64) * 8]);
        }
        __syncthreads();

#pragma unroll
        for (int ks = 0; ks < 2; ++ks) {
            short8 af[4], bfr[4];
#pragma unroll
            for (int i = 0; i < 4; ++i) {
                int r  = wm * 64 + i * 16 + l15;
                int c2 = ks * 8 + quad * 2;          // 16B-chunk index (of 16)
                float4 f0 = *(const float4*)&Asf[r * 64 + ((c2 ^ (r & 15)) * 4)];
                float4 f1 = *(const float4*)&Asf[r * 64 + (((c2 + 1) ^ (r & 15)) * 4)];
                PK4 pk;
                pk.u[0] = cvt_pk_bf16(f0.x, f0.y);
                pk.u[1] = cvt_pk_bf16(f0.z, f0.w);
                pk.u[2] = cvt_pk_bf16(f1.x, f1.y);
                pk.u[3] = cvt_pk_bf16(f1.z, f1.w);
                af[i] = pk.s;
            }
#pragma unroll
            for (int j = 0; j < 4; ++j) {
                int r = wn * 64 + j * 16 + l15;
                int c = ks * 4 + quad;
                bfr[j] = *(const short8*)&Bs[r * 64 + ((c ^ (r & 7)) * 8)];
            }
#pragma unroll
            for (int i = 0; i < 4; ++i)
#pragma unroll
                for (int j = 0; j < 4; ++j)
                    acc[i][j] = __builtin_amdgcn_mfma_f32_16x16x32_bf16(
                        af[i], bfr[j], acc[i][j], 0, 0, 0);
        }
        __syncthreads();
    }

    // C/D layout: col = lane&15, row = quad*4 + reg
#pragma unroll
    for (int j = 0; j < 4; ++j) {
        int col = bn0 + wn * 64 + j * 16 + l15;
        float bb = bias[col];
#pragma unroll
        for (int i = 0; i < 4; ++i) {
            int rowb = bm0 + wm * 64 + i * 16 + quad * 4;
#pragma unroll
            for (int r = 0; r < 4; ++r) {
                float v = acc[i][j][r] + bb;
                size_t idx = (size_t)(rowb + r) * N_DIM + col;
                if (outBf) outBf[idx] = f2bf(v);
                else       outF[idx]  = v;
            }
        }
    }

    // ---- fused chunk-carry epilogue (harness-verified in R1/R2) ----
    // U = (1-a)*sum_{rloc} a^(63-rloc)*acc + bias*(1-a^64), rloc = i*16+quad*4+r
    if (carry) {
        const int bIdx = bm0 >> 10;                       // / T_DIM
        const int g    = ((bm0 & (T_DIM - 1)) >> 6) + wm; // chunk index
#pragma unroll
        for (int j = 0; j < 4; ++j) {
            int col = bn0 + wn * 64 + j * 16 + l15;
            float a   = decay[col];
            float bb  = bias[col];
            float a2  = a * a;
            float a4  = a2 * a2;
            float a8  = a4 * a4;
            float a12 = a8 * a4;
            float a64 = a12 * a4;          // a^16
            a64 = a64 * a64;               // a^32
            a64 = a64 * a64;               // a^64
            float w = (quad == 0) ? a12 : (quad == 1) ? a8
                    : (quad == 2) ? a4  : 1.0f;
            float sacc = 0.f;
#pragma unroll
            for (int i = 3; i >= 0; --i) {
#pragma unroll
                for (int r = 3; r >= 0; --r) {
                    sacc += w * acc[i][j][r];
                    w *= a;
                }
                if (i) w *= a12;           // row gap 13 across fragments
            }
            sacc += __shfl_xor(sacc, 16);
            sacc += __shfl_xor(sacc, 32);
            float U = (1.0f - a) * sacc + bb * (1.0f - a64);
            if (quad == 0)
                carry[((size_t)bIdx * NCHUNK + g) * N_DIM + col] = U;
        }
    }
}

// ---------------------------------------------------------------------------
// Apply pass, 4-wide over o: uint2 loads (8B/lane), float4 stores (16B/lane).
// Thread <-> (b, chunk, o4): o4 = tid&255, chunk = (tid>>8)&15, b = tid>>12.
// 131072 threads = 2048 waves = 8 waves/CU; 32-deep load pipeline (256B/thr).
// ---------------------------------------------------------------------------
__global__ __launch_bounds__(256) void scan_apply4(
    const uint2* __restrict__ cur4,           // [M, N/4] (2x bf16-pair)
    const float* __restrict__ decay,
    const float* __restrict__ carry,          // [B, NCHUNK, N]
    float* __restrict__ out) {                // [M, N] fp32
    int tid   = blockIdx.x * 256 + threadIdx.x;   // 0 .. 131071
    int o4    = tid & 255;
    int chunk = (tid >> 8) & (NCHUNK - 1);
    int b     = tid >> 12;
    int o     = o4 * 4;
    size_t base = ((size_t)b * T_DIM + (size_t)chunk * CHUNK_T) * (N_DIM / 4) + o4;
    float4 av = *(const float4*)&decay[o];
    float a0 = av.x, a1 = av.y, a2 = av.z, a3 = av.w;
    float c0 = 1.f - a0, c1 = 1.f - a1, c2 = 1.f - a2, c3 = 1.f - a3;

    float A0 = a0, A1 = a1, A2 = a2, A3 = a3;
#pragma unroll
    for (int i = 0; i < 6; ++i) { A0 *= A0; A1 *= A1; A2 *= A2; A3 *= A3; }  // a^64

    float u0 = 0.f, u1 = 0.f, u2 = 0.f, u3 = 0.f;
    const float* cb = carry + (size_t)b * NCHUNK * N_DIM + o;
    for (int i = 0; i < chunk; ++i) {         // wave-uniform trip count
        float4 cv = *(const float4*)&cb[(size_t)i * N_DIM];
        u0 = cv.x + A0 * u0;
        u1 = cv.y + A1 * u1;
        u2 = cv.z + A2 * u2;
        u3 = cv.w + A3 * u3;
    }

    float4* out4 = (float4*)out;
    for (int t0 = 0; t0 < CHUNK_T; t0 += 32) {
        uint2 x[32];
#pragma unroll
        for (int k = 0; k < 32; ++k)
            x[k] = cur4[base + (size_t)(t0 + k) * (N_DIM / 4)];
#pragma unroll
        for (int k = 0; k < 32; ++k) {
            float v0 = __uint_as_float(x[k].x << 16);
            float v1 = __uint_as_float(x[k].x & 0xffff0000u);
            float v2 = __uint_as_float(x[k].y << 16);
            float v3 = __uint_as_float(x[k].y & 0xffff0000u);
            u0 = a0 * u0 + c0 * v0;
            u1 = a1 * u1 + c1 * v1;
            u2 = a2 * u2 + c2 * v2;
            u3 = a3 * u3 + c3 * v3;
            out4[base + (size_t)(t0 + k) * (N_DIM / 4)] = (float4){u0, u1, u2, u3};
        }
    }
}

// ---------------------------------------------------------------------------
// Fallbacks (only used if workspace too small for the bf16 path)
// ---------------------------------------------------------------------------
__global__ void scan_f32_inplace(float* __restrict__ buf,
                                 const float* __restrict__ decay) {
    int tid = blockIdx.x * 64 + threadIdx.x;
    int o = tid & (N_DIM - 1);
    size_t base = ((size_t)(tid >> 10) << 20) + o;
    float a = decay[o];
    float c = 1.f - a;
    float u = 0.f;
    for (int t0 = 0; t0 < 1024; t0 += 16) {
        float x[16];
#pragma unroll
        for (int k = 0; k < 16; ++k)
            x[k] = buf[base + (size_t)(t0 + k) * N_DIM];
#pragma unroll
        for (int k = 0; k < 16; ++k) {
            u = a * u + c * x[k];
            buf[base + (size_t)(t0 + k) * N_DIM] = u;
        }
    }
}

__global__ void gemm_naive(const float* __restrict__ X, const float* __restrict__ W,
                           const float* __restrict__ bias, float* __restrict__ out) {
    __shared__ float As[16][17], Bs[16][17];
    int tx = threadIdx.x, ty = threadIdx.y;
    int m0 = blockIdx.y * 16, n0 = blockIdx.x * 16;
    float acc = 0.f;
    for (int k0 = 0; k0 < K_DIM; k0 += 16) {
        As[ty][tx] = X[(size_t)(m0 + ty) * K_DIM + k0 + tx];
        Bs[ty][tx] = W[(size_t)(n0 + ty) * K_DIM + k0 + tx];
        __syncthreads();
#pragma unroll
        for (int kk = 0; kk < 16; ++kk) acc += As[ty][kk] * Bs[tx][kk];
        __syncthreads();
    }
    out[(size_t)(m0 + ty) * N_DIM + n0 + tx] = acc + bias[n0 + tx];
}

// ---------------------------------------------------------------------------
extern "C" void kernel_launch(void* const* d_in, const int* in_sizes, int n_in,
                              void* d_out, int out_size, void* d_ws, size_t ws_size,
                              hipStream_t stream) {
    const float* X     = (const float*)d_in[0];  // [B,T,IN]  = [M,K]
    const float* Wt    = (const float*)d_in[1];  // [OUT,IN]  = [N,K]
    const float* bias  = (const float*)d_in[2];  // [OUT]
    const float* decay = (const float*)d_in[3];  // [OUT]
    float* out = (float*)d_out;                  // [B,T,OUT] = [M,N]

    const size_t W_bytes  = (size_t)N_DIM * K_DIM * 2;            // 2 MB
    const size_t C_bytes  = (size_t)M_DIM * N_DIM * 2;            // 64 MB
    const size_t cr_bytes = (size_t)B_DIM * NCHUNK * N_DIM * 4;   // 2 MB
    const size_t need_mid  = W_bytes;
    const size_t need_full = W_bytes + C_bytes + cr_bytes;

    const int nW8 = N_DIM * K_DIM / 8;

    if (ws_size >= need_full) {
        unsigned short* Wbf = (unsigned short*)d_ws;
        unsigned short* Cbf = (unsigned short*)((char*)d_ws + W_bytes);
        float* carry = (float*)((char*)d_ws + W_bytes + C_bytes);
        cast_f32_bf16_x8<<<(nW8 + 255) / 256, 256, 0, stream>>>(Wt, Wbf, nW8);
        gemm_mfma_f32lds<<<dim3(N_DIM / 128, M_DIM / 128), 256, 0, stream>>>(
            X, Wbf, bias, decay, Cbf, nullptr, carry);
        const int apply_threads = B_DIM * NCHUNK * N_DIM / 4;     // 131072
        scan_apply4<<<apply_threads / 256, 256, 0, stream>>>(
            (const uint2*)Cbf, decay, carry, out);
    } else if (ws_size >= need_mid) {
        unsigned short* Wbf = (unsigned short*)d_ws;
        cast_f32_bf16_x8<<<(nW8 + 255) / 256, 256, 0, stream>>>(Wt, Wbf, nW8);
        gemm_mfma_f32lds<<<dim3(N_DIM / 128, M_DIM / 128), 256, 0, stream>>>(
            X, Wbf, bias, decay, nullptr, out, nullptr);
        scan_f32_inplace<<<512, 64, 0, stream>>>(out, decay);
    } else {
        gemm_naive<<<dim3(N_DIM / 16, M_DIM / 16), dim3(16, 16), 0, stream>>>(X, Wt, bias, out);
        scan_f32_inplace<<<512, 64, 0, stream>>>(out, decay);
    }
}

// Round 4
// 341.100 us; speedup vs baseline: 1.1197x; 1.1183x over previous
//
#include <hip/hip_runtime.h>

// Problem constants: B=32, T=1024, IN=1024, OUT=1024
// M = B*T = 32768, K = IN = 1024, N = OUT = 1024
#define M_DIM 32768
#define N_DIM 1024
#define K_DIM 1024
#define T_DIM 1024
#define B_DIM 32
#define NCHUNK 16
#define CHUNK_T 64    // T_DIM / NCHUNK; one chunk per GEMM wave-half (wm)

typedef unsigned int uint32;
typedef __attribute__((ext_vector_type(8))) short short8;       // 8 bf16 (MFMA A/B frag)
typedef __attribute__((ext_vector_type(8))) unsigned short ushort8v;
typedef __attribute__((ext_vector_type(4))) float floatx4;      // MFMA C/D frag

__device__ __forceinline__ unsigned short f2bf(float f) {
    uint32 u = __float_as_uint(f);
    uint32 r = u + 0x7fffu + ((u >> 16) & 1u);
    return (unsigned short)(r >> 16);
}

__device__ __forceinline__ void async_load16(const void* g, void* s) {
    __builtin_amdgcn_global_load_lds(
        (const __attribute__((address_space(1))) void*)g,
        (__attribute__((address_space(3))) void*)s,
        16, 0, 0);
}

// ---------------------------------------------------------------------------
// Fused fp32 -> bf16 cast for A and W in one dispatch (R1-verified).
// ---------------------------------------------------------------------------
__global__ void cast_f32_bf16_fused(const float* __restrict__ X,
                                    const float* __restrict__ Wt,
                                    unsigned short* __restrict__ dst,
                                    int nA8, int nTot8) {
    int i = blockIdx.x * blockDim.x + threadIdx.x;
    if (i < nTot8) {
        const float* src = (i < nA8) ? (X + (size_t)i * 8)
                                     : (Wt + (size_t)(i - nA8) * 8);
        float4 v0 = ((const float4*)src)[0];
        float4 v1 = ((const float4*)src)[1];
        ushort8v o;
        o[0] = f2bf(v0.x); o[1] = f2bf(v0.y); o[2] = f2bf(v0.z); o[3] = f2bf(v0.w);
        o[4] = f2bf(v1.x); o[5] = f2bf(v1.y); o[6] = f2bf(v1.z); o[7] = f2bf(v1.w);
        ((ushort8v*)dst)[i] = o;
    }
}

// ---------------------------------------------------------------------------
// bf16 MFMA GEMM, DOUBLE-BUFFERED (T3-minimum): next k-tile's
// global_load_lds issues BEFORE the current tile's ds_read+MFMA, one
// __syncthreads() per k-tile (compiler-inserted vmcnt(0) drain waits on
// loads that were in flight during the whole compute phase). Two named
// buffer pairs -> distinct LDS symbols -> no spurious alias waits.
// Core math, swizzle, XCD remap, and carry epilogue identical to the
// harness-verified R1 kernel.
// ---------------------------------------------------------------------------
#define STAGE_TILE(AsD, BsD, k0)                                          \
  {                                                                       \
    _Pragma("unroll")                                                     \
    for (int q = 0; q < 4; ++q) {                                         \
      int slot = q * 256 + tid;                                           \
      int row  = slot >> 3;                                               \
      int ch   = slot & 7;                                                \
      int sc   = ch ^ (row & 7);                                          \
      async_load16(Ag + (size_t)(bm0 + row) * K_DIM + (k0) + sc * 8,      \
                   &AsD[(q * 256 + wid * 64) * 8]);                       \
    }                                                                     \
    _Pragma("unroll")                                                     \
    for (int q = 0; q < 4; ++q) {                                         \
      int slot = q * 256 + tid;                                           \
      int row  = slot >> 3;                                               \
      int ch   = slot & 7;                                                \
      int sc   = ch ^ (row & 7);                                          \
      async_load16(Bg + (size_t)(bn0 + row) * K_DIM + (k0) + sc * 8,      \
                   &BsD[(q * 256 + wid * 64) * 8]);                       \
    }                                                                     \
  }

#define COMPUTE_TILE(AsS, BsS)                                            \
  {                                                                       \
    _Pragma("unroll")                                                     \
    for (int ks = 0; ks < 2; ++ks) {                                      \
      short8 af[4], bfr[4];                                               \
      _Pragma("unroll")                                                   \
      for (int i = 0; i < 4; ++i) {                                       \
        int r = wm * 64 + i * 16 + l15;                                   \
        int c = ks * 4 + quad;                                            \
        af[i] = *(const short8*)&AsS[r * 64 + ((c ^ (r & 7)) * 8)];       \
      }                                                                   \
      _Pragma("unroll")                                                   \
      for (int j = 0; j < 4; ++j) {                                       \
        int r = wn * 64 + j * 16 + l15;                                   \
        int c = ks * 4 + quad;                                            \
        bfr[j] = *(const short8*)&BsS[r * 64 + ((c ^ (r & 7)) * 8)];      \
      }                                                                   \
      _Pragma("unroll")                                                   \
      for (int i = 0; i < 4; ++i)                                         \
        _Pragma("unroll")                                                 \
        for (int j = 0; j < 4; ++j)                                       \
          acc[i][j] = __builtin_amdgcn_mfma_f32_16x16x32_bf16(            \
              af[i], bfr[j], acc[i][j], 0, 0, 0);                         \
    }                                                                     \
  }

__global__ __launch_bounds__(256) void gemm_mfma_db(
    const unsigned short* __restrict__ Ag,  // [M, K] bf16
    const unsigned short* __restrict__ Bg,  // [N, K] bf16
    const float* __restrict__ bias,         // [N]
    const float* __restrict__ decay,        // [N]
    unsigned short* outBf,                  // [M, N] bf16 (or null)
    float* outF,                            // [M, N] fp32 (or null)
    float* carry) {                         // [B, NCHUNK, N] (or null)
    __shared__ unsigned short As0[128 * 64];
    __shared__ unsigned short Bs0[128 * 64];
    __shared__ unsigned short As1[128 * 64];
    __shared__ unsigned short Bs1[128 * 64];

    const int tid  = threadIdx.x;
    const int lane = tid & 63;
    const int wid  = tid >> 6;
    const int l15  = lane & 15;
    const int quad = lane >> 4;
    const int wm   = wid >> 1;
    const int wn   = wid & 1;

    // XCD-aware remap (grid is (8, 256) -> L in [0, 2048))
    const int L    = blockIdx.y * gridDim.x + blockIdx.x;
    const int xcd  = L & 7;
    const int s    = L >> 3;
    const int bn0  = (s & 7) * 128;                 // N-tile
    const int bm0  = (xcd * 32 + (s >> 3)) * 128;   // M-panel

    floatx4 acc[4][4];
#pragma unroll
    for (int i = 0; i < 4; ++i)
#pragma unroll
        for (int j = 0; j < 4; ++j)
            acc[i][j] = (floatx4){0.f, 0.f, 0.f, 0.f};

    // Prologue: stage tile 0 into buffer 0.
    STAGE_TILE(As0, Bs0, 0);
    __syncthreads();

    // 16 k-tiles, processed 2 per unrolled iteration (ping/pong).
#pragma unroll 1
    for (int kt = 0; kt < K_DIM / 64; kt += 2) {
        STAGE_TILE(As1, Bs1, (kt + 1) * 64);    // in flight during compute
        COMPUTE_TILE(As0, Bs0);
        __syncthreads();                        // drains vmcnt + syncs buf0 reuse
        if (kt + 2 < K_DIM / 64)
            STAGE_TILE(As0, Bs0, (kt + 2) * 64);
        COMPUTE_TILE(As1, Bs1);
        __syncthreads();
    }

    // C/D layout: col = lane&15, row = quad*4 + reg
#pragma unroll
    for (int j = 0; j < 4; ++j) {
        int col = bn0 + wn * 64 + j * 16 + l15;
        float bb = bias[col];
#pragma unroll
        for (int i = 0; i < 4; ++i) {
            int rowb = bm0 + wm * 64 + i * 16 + quad * 4;
#pragma unroll
            for (int r = 0; r < 4; ++r) {
                float v = acc[i][j][r] + bb;
                size_t idx = (size_t)(rowb + r) * N_DIM + col;
                if (outBf) outBf[idx] = f2bf(v);
                else       outF[idx]  = v;
            }
        }
    }

    // ---- fused chunk-carry epilogue (harness-verified R1/R2/R3) ----
    // U = (1-a)*sum_{rloc} a^(63-rloc)*acc + bias*(1-a^64), rloc = i*16+quad*4+r
    if (carry) {
        const int bIdx = bm0 >> 10;                       // / T_DIM
        const int g    = ((bm0 & (T_DIM - 1)) >> 6) + wm; // chunk index
#pragma unroll
        for (int j = 0; j < 4; ++j) {
            int col = bn0 + wn * 64 + j * 16 + l15;
            float a   = decay[col];
            float bb  = bias[col];
            float a2  = a * a;
            float a4  = a2 * a2;
            float a8  = a4 * a4;
            float a12 = a8 * a4;
            float a64 = a12 * a4;          // a^16
            a64 = a64 * a64;               // a^32
            a64 = a64 * a64;               // a^64
            float w = (quad == 0) ? a12 : (quad == 1) ? a8
                    : (quad == 2) ? a4  : 1.0f;
            float sacc = 0.f;
#pragma unroll
            for (int i = 3; i >= 0; --i) {
#pragma unroll
                for (int r = 3; r >= 0; --r) {
                    sacc += w * acc[i][j][r];
                    w *= a;
                }
                if (i) w *= a12;           // row gap 13 across fragments
            }
            sacc += __shfl_xor(sacc, 16);
            sacc += __shfl_xor(sacc, 32);
            float U = (1.0f - a) * sacc + bb * (1.0f - a64);
            if (quad == 0)
                carry[((size_t)bIdx * NCHUNK + g) * N_DIM + col] = U;
        }
    }
}

// ---------------------------------------------------------------------------
// Apply pass, 4-wide over o: uint2 loads (8B/lane), float4 stores (16B/lane).
// Thread <-> (b, chunk, o4): o4 = tid&255, chunk = (tid>>8)&15, b = tid>>12.
// 131072 threads = 2048 waves = 8 waves/CU; 32-deep load pipeline.
// ---------------------------------------------------------------------------
__global__ __launch_bounds__(256) void scan_apply4(
    const uint2* __restrict__ cur4,           // [M, N/4] (2x bf16-pair)
    const float* __restrict__ decay,
    const float* __restrict__ carry,          // [B, NCHUNK, N]
    float* __restrict__ out) {                // [M, N] fp32
    int tid   = blockIdx.x * 256 + threadIdx.x;   // 0 .. 131071
    int o4    = tid & 255;
    int chunk = (tid >> 8) & (NCHUNK - 1);
    int b     = tid >> 12;
    int o     = o4 * 4;
    size_t base = ((size_t)b * T_DIM + (size_t)chunk * CHUNK_T) * (N_DIM / 4) + o4;
    float4 av = *(const float4*)&decay[o];
    float a0 = av.x, a1 = av.y, a2 = av.z, a3 = av.w;
    float c0 = 1.f - a0, c1 = 1.f - a1, c2 = 1.f - a2, c3 = 1.f - a3;

    float A0 = a0, A1 = a1, A2 = a2, A3 = a3;
#pragma unroll
    for (int i = 0; i < 6; ++i) { A0 *= A0; A1 *= A1; A2 *= A2; A3 *= A3; }  // a^64

    float u0 = 0.f, u1 = 0.f, u2 = 0.f, u3 = 0.f;
    const float* cb = carry + (size_t)b * NCHUNK * N_DIM + o;
    for (int i = 0; i < chunk; ++i) {         // wave-uniform trip count
        float4 cv = *(const float4*)&cb[(size_t)i * N_DIM];
        u0 = cv.x + A0 * u0;
        u1 = cv.y + A1 * u1;
        u2 = cv.z + A2 * u2;
        u3 = cv.w + A3 * u3;
    }

    float4* out4 = (float4*)out;
    for (int t0 = 0; t0 < CHUNK_T; t0 += 32) {
        uint2 x[32];
#pragma unroll
        for (int k = 0; k < 32; ++k)
            x[k] = cur4[base + (size_t)(t0 + k) * (N_DIM / 4)];
#pragma unroll
        for (int k = 0; k < 32; ++k) {
            float v0 = __uint_as_float(x[k].x << 16);
            float v1 = __uint_as_float(x[k].x & 0xffff0000u);
            float v2 = __uint_as_float(x[k].y << 16);
            float v3 = __uint_as_float(x[k].y & 0xffff0000u);
            u0 = a0 * u0 + c0 * v0;
            u1 = a1 * u1 + c1 * v1;
            u2 = a2 * u2 + c2 * v2;
            u3 = a3 * u3 + c3 * v3;
            out4[base + (size_t)(t0 + k) * (N_DIM / 4)] = (float4){u0, u1, u2, u3};
        }
    }
}

// ---------------------------------------------------------------------------
// Fallbacks (only used if workspace too small for the bf16 path)
// ---------------------------------------------------------------------------
__global__ void scan_f32_inplace(float* __restrict__ buf,
                                 const float* __restrict__ decay) {
    int tid = blockIdx.x * 64 + threadIdx.x;
    int o = tid & (N_DIM - 1);
    size_t base = ((size_t)(tid >> 10) << 20) + o;
    float a = decay[o];
    float c = 1.f - a;
    float u = 0.f;
    for (int t0 = 0; t0 < 1024; t0 += 16) {
        float x[16];
#pragma unroll
        for (int k = 0; k < 16; ++k)
            x[k] = buf[base + (size_t)(t0 + k) * N_DIM];
#pragma unroll
        for (int k = 0; k < 16; ++k) {
            u = a * u + c * x[k];
            buf[base + (size_t)(t0 + k) * N_DIM] = u;
        }
    }
}

__global__ void gemm_naive(const float* __restrict__ X, const float* __restrict__ W,
                           const float* __restrict__ bias, float* __restrict__ out) {
    __shared__ float As[16][17], Bs[16][17];
    int tx = threadIdx.x, ty = threadIdx.y;
    int m0 = blockIdx.y * 16, n0 = blockIdx.x * 16;
    float acc = 0.f;
    for (int k0 = 0; k0 < K_DIM; k0 += 16) {
        As[ty][tx] = X[(size_t)(m0 + ty) * K_DIM + k0 + tx];
        Bs[ty][tx] = W[(size_t)(n0 + ty) * K_DIM + k0 + tx];
        __syncthreads();
#pragma unroll
        for (int kk = 0; kk < 16; ++kk) acc += As[ty][kk] * Bs[tx][kk];
        __syncthreads();
    }
    out[(size_t)(m0 + ty) * N_DIM + n0 + tx] = acc + bias[n0 + tx];
}

// ---------------------------------------------------------------------------
extern "C" void kernel_launch(void* const* d_in, const int* in_sizes, int n_in,
                              void* d_out, int out_size, void* d_ws, size_t ws_size,
                              hipStream_t stream) {
    const float* X     = (const float*)d_in[0];  // [B,T,IN]  = [M,K]
    const float* Wt    = (const float*)d_in[1];  // [OUT,IN]  = [N,K]
    const float* bias  = (const float*)d_in[2];  // [OUT]
    const float* decay = (const float*)d_in[3];  // [OUT]
    float* out = (float*)d_out;                  // [B,T,OUT] = [M,N]

    const size_t A_bytes  = (size_t)M_DIM * K_DIM * 2;            // 64 MB
    const size_t W_bytes  = (size_t)N_DIM * K_DIM * 2;            // 2 MB
    const size_t C_bytes  = (size_t)M_DIM * N_DIM * 2;            // 64 MB
    const size_t cr_bytes = (size_t)B_DIM * NCHUNK * N_DIM * 4;   // 2 MB
    const size_t need_mid  = A_bytes + W_bytes;
    const size_t need_full = A_bytes + W_bytes + C_bytes + cr_bytes;

    const int nA8   = M_DIM * K_DIM / 8;
    const int nW8   = N_DIM * K_DIM / 8;
    const int nTot8 = nA8 + nW8;

    if (ws_size >= need_full) {
        unsigned short* Abf = (unsigned short*)d_ws;
        unsigned short* Wbf = (unsigned short*)((char*)d_ws + A_bytes);
        unsigned short* Cbf = (unsigned short*)((char*)d_ws + A_bytes + W_bytes);
        float* carry = (float*)((char*)d_ws + A_bytes + W_bytes + C_bytes);
        cast_f32_bf16_fused<<<(nTot8 + 255) / 256, 256, 0, stream>>>(X, Wt, Abf, nA8, nTot8);
        gemm_mfma_db<<<dim3(N_DIM / 128, M_DIM / 128), 256, 0, stream>>>(
            Abf, Wbf, bias, decay, Cbf, nullptr, carry);
        const int apply_threads = B_DIM * NCHUNK * N_DIM / 4;     // 131072
        scan_apply4<<<apply_threads / 256, 256, 0, stream>>>(
            (const uint2*)Cbf, decay, carry, out);
    } else if (ws_size >= need_mid) {
        unsigned short* Abf = (unsigned short*)d_ws;
        unsigned short* Wbf = (unsigned short*)((char*)d_ws + A_bytes);
        cast_f32_bf16_fused<<<(nTot8 + 255) / 256, 256, 0, stream>>>(X, Wt, Abf, nA8, nTot8);
        gemm_mfma_db<<<dim3(N_DIM / 128, M_DIM / 128), 256, 0, stream>>>(
            Abf, Wbf, bias, decay, nullptr, out, nullptr);
        scan_f32_inplace<<<512, 64, 0, stream>>>(out, decay);
    } else {
        gemm_naive<<<dim3(N_DIM / 16, M_DIM / 16), dim3(16, 16), 0, stream>>>(X, Wt, bias, out);
        scan_f32_inplace<<<512, 64, 0, stream>>>(out, decay);
    }
}